// Round 3
// baseline (389.298 us; speedup 1.0000x reference)
//
#include <hip/hip_runtime.h>

// ============================================================================
// ROUND 3: MEASUREMENT PROBE — kernel launched 5x (idempotent; identical
// writes each time). Purpose: dur_us delta vs round 2 (250.8 us) isolates the
// true kernel dispatch time, which the top-5 counter table cannot show
// (harness fills at ~125 us crowd it out):
//     k_warm = (dur_us - 250.8) / 4
// Kernel body is byte-identical to round 2.
// ============================================================================

// Problem constants (fixed by setup_inputs).
#define B_SZ 4
#define C_CH 12
#define H_G 16
#define W_G 16
#define D_G 8
#define H_IM 1024
#define W_IM 1024

#define CELL_F4 13
// LDS: 16*8 cells * 13 float4 * 16 B = 26624 B -> 6 blocks/CU (LDS-limited)

typedef float vfloat4 __attribute__((ext_vector_type(4)));

__global__ __launch_bounds__(256) void bilateral_slice_kernel(
    const float* __restrict__ grid,
    const float* __restrict__ guide,
    float* __restrict__ out)
{
    __shared__ float4 Qs[H_G * D_G * CELL_F4];

    const int blk = blockIdx.x;
    const int b = blk >> 10;      // blk / H_IM
    const int i = blk & 1023;     // blk % H_IM
    const int t = threadIdx.x;

    // Row-constant grid-W coordinate (reference: ww = i/(H-1) * (Wg-1)).
    const float wwv = ((float)i / 1023.0f) * 15.0f;
    const float w0f = floorf(wwv);
    const int   w0  = (int)w0f;
    const int   w1  = min(w0 + 1, W_G - 1);
    const float fw  = wwv - w0f;

    // ---- Precompute quad-cells: thread t -> (channel c, grid-row h) ----
    if (t < C_CH * H_G) {
        const int c  = t >> 4;    // t / 16
        const int h  = t & 15;    // t % 16
        const int h1 = min(h + 1, H_G - 1);
        const float* r0 = grid + (((size_t)(b * C_CH + c) * H_G + h ) * W_G) * D_G;
        const float* r1 = grid + (((size_t)(b * C_CH + c) * H_G + h1) * W_G) * D_G;
        const int o0 = w0 * D_G;
        const int o1 = w1 * D_G;
        float A[8], Bv[8], Cv[8], Dv[8];
        *(float4*)&A [0] = *(const float4*)(r0 + o0);
        *(float4*)&A [4] = *(const float4*)(r0 + o0 + 4);
        *(float4*)&Bv[0] = *(const float4*)(r0 + o1);
        *(float4*)&Bv[4] = *(const float4*)(r0 + o1 + 4);
        *(float4*)&Cv[0] = *(const float4*)(r1 + o0);
        *(float4*)&Cv[4] = *(const float4*)(r1 + o0 + 4);
        *(float4*)&Dv[0] = *(const float4*)(r1 + o1);
        *(float4*)&Dv[4] = *(const float4*)(r1 + o1 + 4);
        float P[8], P1[8];
        #pragma unroll
        for (int d = 0; d < 8; ++d) {
            P [d] = A [d] + fw * (Bv[d] - A [d]);   // w-lerp @ h
            P1[d] = Cv[d] + fw * (Dv[d] - Cv[d]);   // w-lerp @ h1
        }
        float4* cell = &Qs[(h * D_G) * CELL_F4 + c];
        #pragma unroll
        for (int d = 0; d < 8; ++d) {
            const int dn = (d < 7) ? d + 1 : 7;
            cell[d * CELL_F4] = make_float4(P[d], P[dn], P1[d], P1[dn]);
        }
    }
    __syncthreads();

    // ---- Main: 4 consecutive pixels per thread, all 12 channels ----
    const int j0 = t << 2;
    const float4 g4 = *(const float4*)(guide + ((size_t)b * H_IM + i) * W_IM + j0);

    float wA[4], wB[4], wC[4], wD[4];
    int   boff[4];                // byte offset of this pixel's quad-cell in Qs
    #pragma unroll
    for (int p = 0; p < 4; ++p) {
        const float gval = (p == 0) ? g4.x : (p == 1) ? g4.y : (p == 2) ? g4.z : g4.w;
        const float dc  = gval * 7.0f;
        float dlf = floorf(dc);
        dlf = fminf(fmaxf(dlf, 0.0f), 7.0f);
        const int   dlo = (int)dlf;
        const float dw  = fminf(fmaxf(dc - dlf, 0.0f), 1.0f);
        const int   j   = j0 + p;
        const float hhv = ((float)j / 1023.0f) * 15.0f;
        const float h0f = floorf(hhv);
        const int   h0  = (int)h0f;
        const float fh  = hhv - h0f;

        wA[p] = (1.0f - fh) * (1.0f - dw);
        wB[p] = (1.0f - fh) * dw;
        wC[p] = fh * (1.0f - dw);
        wD[p] = fh * dw;
        boff[p] = (h0 * D_G + dlo) * (CELL_F4 * 16);
    }

    const char* lds_base = (const char*)Qs;
    float* outp = out + (((size_t)b * C_CH) * H_IM + i) * W_IM + j0;

    #pragma unroll
    for (int c = 0; c < C_CH; ++c) {
        vfloat4 v;
        #pragma unroll
        for (int p = 0; p < 4; ++p) {
            const float4 q = *(const float4*)(lds_base + boff[p] + c * 16);
            v[p] = wA[p] * q.x + wB[p] * q.y + wC[p] * q.z + wD[p] * q.w;
        }
        *(vfloat4*)(outp + (size_t)c * (H_IM * W_IM)) = v;
        if ((c % 3) == 2) __builtin_amdgcn_sched_barrier(0);
    }
}

extern "C" void kernel_launch(void* const* d_in, const int* in_sizes, int n_in,
                              void* d_out, int out_size, void* d_ws, size_t ws_size,
                              hipStream_t stream) {
    const float* grid  = (const float*)d_in[0];
    const float* guide = (const float*)d_in[1];
    float* out = (float*)d_out;

    const int nblocks = B_SZ * H_IM;   // one block per (b, row)
    // PROBE: 5 identical launches. Writes are idempotent, so output stays
    // correct; (dur_us - 250.8)/4 gives the warm per-dispatch kernel time.
    #pragma unroll
    for (int rep = 0; rep < 5; ++rep) {
        bilateral_slice_kernel<<<nblocks, 256, 0, stream>>>(grid, guide, out);
    }
}

// Round 4
// 250.637 us; speedup vs baseline: 1.5532x; 1.5532x over previous
//
#include <hip/hip_runtime.h>

// ============================================================================
// Final kernel (round-2 body, single launch restored after the round-3 5x
// timing probe). Probe result: warm kernel = (389.3-250.8)/4 = 34.6 us, which
// equals the HBM roofline exactly (201 MB stores + 17 MB guide reads = 218 MB
// @ 6.3 TB/s achievable = 34.6 us). Remaining ~216 us of the timed graph is
// harness-side poison-fill/reset traffic, not addressable from the kernel.
// ============================================================================

// Problem constants (fixed by setup_inputs).
#define B_SZ 4
#define C_CH 12
#define H_G 16
#define W_G 16
#define D_G 8
#define H_IM 1024
#define W_IM 1024

// Quad-cell LDS layout: cell(h,d) holds, for each channel c, the float4
//   { P[h][d], P[h][dn], P[h1][d], P[h1][dn] }   (dn=min(d+1,7), h1=min(h+1,15))
// where P is the grid row already lerped along Wg for this image row.
// One ds_read_b128 + 4 FMA gives one pixel-channel output.
// Cell stride 13 float4 (208 B): bank-quad = (52*(8h+d)+4c) mod 32 spreads d
// over all 8 quad positions (52*d mod 32 = {0,20,8,28,16,4,24,12}).
#define CELL_F4 13
// LDS: 16*8 cells * 13 float4 * 16 B = 26624 B -> 6 blocks/CU (LDS-limited)

typedef float vfloat4 __attribute__((ext_vector_type(4)));

__global__ __launch_bounds__(256) void bilateral_slice_kernel(
    const float* __restrict__ grid,
    const float* __restrict__ guide,
    float* __restrict__ out)
{
    __shared__ float4 Qs[H_G * D_G * CELL_F4];

    const int blk = blockIdx.x;
    const int b = blk >> 10;      // blk / H_IM
    const int i = blk & 1023;     // blk % H_IM
    const int t = threadIdx.x;

    // Row-constant grid-W coordinate (reference: ww = i/(H-1) * (Wg-1)).
    const float wwv = ((float)i / 1023.0f) * 15.0f;
    const float w0f = floorf(wwv);
    const int   w0  = (int)w0f;
    const int   w1  = min(w0 + 1, W_G - 1);
    const float fw  = wwv - w0f;

    // ---- Precompute quad-cells: thread t -> (channel c, grid-row h) ----
    if (t < C_CH * H_G) {
        const int c  = t >> 4;    // t / 16
        const int h  = t & 15;    // t % 16
        const int h1 = min(h + 1, H_G - 1);
        const float* r0 = grid + (((size_t)(b * C_CH + c) * H_G + h ) * W_G) * D_G;
        const float* r1 = grid + (((size_t)(b * C_CH + c) * H_G + h1) * W_G) * D_G;
        const int o0 = w0 * D_G;
        const int o1 = w1 * D_G;
        float A[8], Bv[8], Cv[8], Dv[8];
        *(float4*)&A [0] = *(const float4*)(r0 + o0);
        *(float4*)&A [4] = *(const float4*)(r0 + o0 + 4);
        *(float4*)&Bv[0] = *(const float4*)(r0 + o1);
        *(float4*)&Bv[4] = *(const float4*)(r0 + o1 + 4);
        *(float4*)&Cv[0] = *(const float4*)(r1 + o0);
        *(float4*)&Cv[4] = *(const float4*)(r1 + o0 + 4);
        *(float4*)&Dv[0] = *(const float4*)(r1 + o1);
        *(float4*)&Dv[4] = *(const float4*)(r1 + o1 + 4);
        float P[8], P1[8];
        #pragma unroll
        for (int d = 0; d < 8; ++d) {
            P [d] = A [d] + fw * (Bv[d] - A [d]);   // w-lerp @ h
            P1[d] = Cv[d] + fw * (Dv[d] - Cv[d]);   // w-lerp @ h1
        }
        float4* cell = &Qs[(h * D_G) * CELL_F4 + c];
        #pragma unroll
        for (int d = 0; d < 8; ++d) {
            const int dn = (d < 7) ? d + 1 : 7;
            cell[d * CELL_F4] = make_float4(P[d], P[dn], P1[d], P1[dn]);
        }
    }
    __syncthreads();

    // ---- Main: 4 consecutive pixels per thread, all 12 channels ----
    const int j0 = t << 2;
    const float4 g4 = *(const float4*)(guide + ((size_t)b * H_IM + i) * W_IM + j0);

    float wA[4], wB[4], wC[4], wD[4];
    int   boff[4];                // byte offset of this pixel's quad-cell in Qs
    #pragma unroll
    for (int p = 0; p < 4; ++p) {
        const float gval = (p == 0) ? g4.x : (p == 1) ? g4.y : (p == 2) ? g4.z : g4.w;
        // depth coordinate (reference: clip(floor(g*7),0,7), clip(frac,0,1))
        const float dc  = gval * 7.0f;
        float dlf = floorf(dc);
        dlf = fminf(fmaxf(dlf, 0.0f), 7.0f);
        const int   dlo = (int)dlf;
        const float dw  = fminf(fmaxf(dc - dlf, 0.0f), 1.0f);
        // grid-H coordinate from column j (reference: hh = j/(W-1) * (Hg-1))
        const int   j   = j0 + p;
        const float hhv = ((float)j / 1023.0f) * 15.0f;
        const float h0f = floorf(hhv);
        const int   h0  = (int)h0f;
        const float fh  = hhv - h0f;

        wA[p] = (1.0f - fh) * (1.0f - dw);
        wB[p] = (1.0f - fh) * dw;
        wC[p] = fh * (1.0f - dw);
        wD[p] = fh * dw;
        boff[p] = (h0 * D_G + dlo) * (CELL_F4 * 16);
    }

    const char* lds_base = (const char*)Qs;
    float* outp = out + (((size_t)b * C_CH) * H_IM + i) * W_IM + j0;

    #pragma unroll
    for (int c = 0; c < C_CH; ++c) {
        vfloat4 v;
        #pragma unroll
        for (int p = 0; p < 4; ++p) {
            const float4 q = *(const float4*)(lds_base + boff[p] + c * 16);
            v[p] = wA[p] * q.x + wB[p] * q.y + wC[p] * q.z + wD[p] * q.w;
        }
        *(vfloat4*)(outp + (size_t)c * (H_IM * W_IM)) = v;
        if ((c % 3) == 2) __builtin_amdgcn_sched_barrier(0);
    }
}

extern "C" void kernel_launch(void* const* d_in, const int* in_sizes, int n_in,
                              void* d_out, int out_size, void* d_ws, size_t ws_size,
                              hipStream_t stream) {
    const float* grid  = (const float*)d_in[0];
    const float* guide = (const float*)d_in[1];
    // d_in[2] (input_image) is only used for its shape in the reference.
    float* out = (float*)d_out;

    const int nblocks = B_SZ * H_IM;   // one block per (b, row)
    bilateral_slice_kernel<<<nblocks, 256, 0, stream>>>(grid, guide, out);
}